// Round 8
// baseline (188.745 us; speedup 1.0000x reference)
//
#include <hip/hip_runtime.h>
#include <math.h>

#define Bn 2
#define Sn 2048
#define Dn 1024
#define Hn 16
#define DKn 64
#define Mn (Bn*Sn)

typedef __bf16 bf16;
typedef __attribute__((ext_vector_type(8))) __bf16 bf16x8;
typedef __attribute__((ext_vector_type(4))) __bf16 bf16x4;
typedef __attribute__((ext_vector_type(4))) float f32x4;
typedef __attribute__((ext_vector_type(16))) float f32x16;

__device__ inline f32x4 mfma16(bf16x8 a, bf16x8 b, f32x4 c) {
    return __builtin_amdgcn_mfma_f32_16x16x32_bf16(a, b, c, 0, 0, 0);
}
__device__ inline f32x16 mfma32(bf16x8 a, bf16x8 b, f32x16 c) {
    return __builtin_amdgcn_mfma_f32_32x32x16_bf16(a, b, c, 0, 0, 0);
}

typedef __attribute__((address_space(3))) void lds_t;
typedef const __attribute__((address_space(1))) void gbl_t;
__device__ __forceinline__ void glds16(const void* g, void* l) {
    __builtin_amdgcn_global_load_lds((gbl_t*)g, (lds_t*)l, 16, 0, 0);
}

// ---------- converts ----------
__global__ __launch_bounds__(256)
void conv3(const float* __restrict__ s0, const float* __restrict__ s1,
           const float* __restrict__ s2, bf16* __restrict__ d0,
           bf16* __restrict__ d1, bf16* __restrict__ d2)
{
    const float* s = blockIdx.y == 0 ? s0 : blockIdx.y == 1 ? s1 : s2;
    bf16*       d = blockIdx.y == 0 ? d0 : blockIdx.y == 1 ? d1 : d2;
    int i = (blockIdx.x * 256 + threadIdx.x) * 8;
    float4 a = *(const float4*)(s + i);
    float4 b = *(const float4*)(s + i + 4);
    bf16x8 o;
    o[0]=(bf16)a.x; o[1]=(bf16)a.y; o[2]=(bf16)a.z; o[3]=(bf16)a.w;
    o[4]=(bf16)b.x; o[5]=(bf16)b.y; o[6]=(bf16)b.z; o[7]=(bf16)b.w;
    *(bf16x8*)(d + i) = o;
}

__global__ __launch_bounds__(256)
void conv_w(const float* __restrict__ s0, const float* __restrict__ s1,
            const float* __restrict__ s2, const float* __restrict__ s3,
            bf16* __restrict__ d0, bf16* __restrict__ d1,
            bf16* __restrict__ d2, bf16* __restrict__ d3)
{
    const float* s = blockIdx.y == 0 ? s0 : blockIdx.y == 1 ? s1 :
                     blockIdx.y == 2 ? s2 : s3;
    bf16*       d = blockIdx.y == 0 ? d0 : blockIdx.y == 1 ? d1 :
                     blockIdx.y == 2 ? d2 : d3;
    int i = (blockIdx.x * 256 + threadIdx.x) * 8;
    float4 a = *(const float4*)(s + i);
    float4 b = *(const float4*)(s + i + 4);
    bf16x8 o;
    o[0]=(bf16)a.x; o[1]=(bf16)a.y; o[2]=(bf16)a.z; o[3]=(bf16)a.w;
    o[4]=(bf16)b.x; o[5]=(bf16)b.y; o[6]=(bf16)b.z; o[7]=(bf16)b.w;
    *(bf16x8*)(d + i) = o;
}

// ---------- projection GEMM ----------
// z==0: out bf16 [B,H,S,DK] scaled 0.125*log2(e) (folds QK scale + exp->exp2);
// z==1: [B,H,S,DK]; z==2: [B,H,DK,S].
__global__ __launch_bounds__(256)
void gemm_proj(const bf16* __restrict__ Aq, const bf16* __restrict__ Ak,
               const bf16* __restrict__ Av, const bf16* __restrict__ Wq,
               const bf16* __restrict__ Wk, const bf16* __restrict__ Wv,
               const float* __restrict__ bq, const float* __restrict__ bk,
               const float* __restrict__ bv,
               bf16* __restrict__ Cq, bf16* __restrict__ Ck, bf16* __restrict__ Cv)
{
    __shared__ bf16 As[128][32];
    __shared__ bf16 Ws_[128][32];

    const int bid = blockIdx.x;
    const int l   = (bid & 7) * 96 + (bid >> 3);
    const int z   = l >> 8;
    const int rem = l & 255;
    const int m0  = (rem >> 3) * 128;
    const int n0  = (rem & 7) * 128;

    const bf16*  A    = z == 0 ? Aq : z == 1 ? Ak : Av;
    const bf16*  W    = z == 0 ? Wq : z == 1 ? Wk : Wv;
    const float* bias = z == 0 ? bq : z == 1 ? bk : bv;
    bf16*        C    = z == 0 ? Cq : z == 1 ? Ck : Cv;
    const float  osc  = (z == 0) ? 0.18033688011112042f : 1.0f;  // log2(e)/8

    const int tid = threadIdx.x;
    const int w4 = tid >> 6, ln = tid & 63;
    const int p = ln & 15, g = ln >> 4;
    const int wr = w4 >> 1, wc = w4 & 1;

    const int arow = w4 * 32 + (ln >> 2);
    const int acol = (ln & 3) * 8;
    const bf16* ga = A + (size_t)(m0 + arow) * Dn + acol;
    const bf16* gw = W + (size_t)(n0 + arow) * Dn + acol;

    f32x4 acc[4][4];
    #pragma unroll
    for (int mi = 0; mi < 4; ++mi)
        #pragma unroll
        for (int ni = 0; ni < 4; ++ni) acc[mi][ni] = (f32x4){0.f,0.f,0.f,0.f};

    for (int k0 = 0; k0 < Dn; k0 += 32) {
        __syncthreads();
        glds16(ga + k0,           &As [w4*32     ][0]);
        glds16(ga + k0 + 16*Dn,   &As [w4*32 + 16][0]);
        glds16(gw + k0,           &Ws_[w4*32     ][0]);
        glds16(gw + k0 + 16*Dn,   &Ws_[w4*32 + 16][0]);
        __syncthreads();

        bf16x8 af[4], bfr[4];
        #pragma unroll
        for (int mi = 0; mi < 4; ++mi)
            af[mi] = *(const bf16x8*)&As[wr*64 + mi*16 + p][g*8];
        #pragma unroll
        for (int ni = 0; ni < 4; ++ni)
            bfr[ni] = *(const bf16x8*)&Ws_[wc*64 + ni*16 + p][g*8];
        #pragma unroll
        for (int mi = 0; mi < 4; ++mi)
            #pragma unroll
            for (int ni = 0; ni < 4; ++ni)
                acc[mi][ni] = mfma16(af[mi], bfr[ni], acc[mi][ni]);
    }

    if (z <= 1) {
        #pragma unroll
        for (int ni = 0; ni < 4; ++ni) {
            int n = n0 + wc*64 + ni*16 + p;
            int h = n >> 6, dk = n & (DKn - 1);
            float bv = bias[n];
            #pragma unroll
            for (int mi = 0; mi < 4; ++mi)
                #pragma unroll
                for (int r = 0; r < 4; ++r) {
                    int m = m0 + wr*64 + mi*16 + 4*g + r;
                    int b = m >> 11, s = m & (Sn - 1);
                    C[(((size_t)(b*Hn + h)*Sn + s)*DKn) + dk] =
                        (bf16)((acc[mi][ni][r] + bv) * osc);
                }
        }
    } else {
        #pragma unroll
        for (int ni = 0; ni < 4; ++ni) {
            int n = n0 + wc*64 + ni*16 + p;
            int h = n >> 6, dk = n & (DKn - 1);
            float bv = bias[n];
            #pragma unroll
            for (int mi = 0; mi < 4; ++mi)
                #pragma unroll
                for (int r = 0; r < 4; ++r) {
                    int m = m0 + wr*64 + mi*16 + 4*g + r;
                    int b = m >> 11, s = m & (Sn - 1);
                    C[(((size_t)(b*Hn + h)*DKn + dk)*Sn) + s] =
                        (bf16)(acc[mi][ni][r] + bv);
                }
        }
    }
}

// ---------- output GEMM (unchanged) ----------
__global__ __launch_bounds__(256)
void gemm_out(const bf16* __restrict__ A, const bf16* __restrict__ W,
              const float* __restrict__ bias, float* __restrict__ C)
{
    __shared__ bf16 As[128][32];
    __shared__ bf16 Ws_[64][32];

    const int bid = blockIdx.x;
    const int l   = (bid & 7) * 64 + (bid >> 3);
    const int m0  = (l >> 4) * 128;
    const int n0  = (l & 15) * 64;

    const int tid = threadIdx.x;
    const int w4 = tid >> 6, ln = tid & 63;
    const int p = ln & 15, g = ln >> 4;
    const int wr = w4 >> 1, wc = w4 & 1;

    const int arow = w4 * 32 + (ln >> 2);
    const int acol = (ln & 3) * 8;
    const bf16* ga = A + (size_t)(m0 + arow) * Dn + acol;
    const bf16* gw = W + (size_t)(n0 + w4*16 + (ln >> 2)) * Dn + acol;

    f32x4 acc[4][2];
    #pragma unroll
    for (int mi = 0; mi < 4; ++mi)
        #pragma unroll
        for (int ni = 0; ni < 2; ++ni) acc[mi][ni] = (f32x4){0.f,0.f,0.f,0.f};

    for (int k0 = 0; k0 < Dn; k0 += 32) {
        __syncthreads();
        glds16(ga + k0,          &As [w4*32     ][0]);
        glds16(ga + k0 + 16*Dn,  &As [w4*32 + 16][0]);
        glds16(gw + k0,          &Ws_[w4*16     ][0]);
        __syncthreads();

        bf16x8 af[4], bfr[2];
        #pragma unroll
        for (int mi = 0; mi < 4; ++mi)
            af[mi] = *(const bf16x8*)&As[wr*64 + mi*16 + p][g*8];
        #pragma unroll
        for (int ni = 0; ni < 2; ++ni)
            bfr[ni] = *(const bf16x8*)&Ws_[wc*32 + ni*16 + p][g*8];
        #pragma unroll
        for (int mi = 0; mi < 4; ++mi)
            #pragma unroll
            for (int ni = 0; ni < 2; ++ni)
                acc[mi][ni] = mfma16(af[mi], bfr[ni], acc[mi][ni]);
    }

    #pragma unroll
    for (int ni = 0; ni < 2; ++ni) {
        int n = n0 + wc*32 + ni*16 + p;
        float bv = bias[n];
        #pragma unroll
        for (int mi = 0; mi < 4; ++mi)
            #pragma unroll
            for (int r = 0; r < 4; ++r) {
                int m = m0 + wr*64 + mi*16 + 4*g + r;
                C[(size_t)m * Dn + n] = acc[mi][ni][r] + bv;
            }
    }
}

// ---------- MFMA flash attention: 32x32 MFMA, swapped QK^T, dbuf K/V ----------
// 256 thr = 4 waves x 32 q-rows = 128 q/block; grid 512 (2 blocks/CU).
// Wave covers 2x the q-rows per K/V LDS read vs 16x16 -> per-CU LDS traffic halves.
// mfma_32x32x16: C col=lane&31, row=(r&3)+8*(r>>2)+4*(lane>>5); A row=lane&31,
// k=8*(lane>>5)+e; B col=lane&31, k=8*(lane>>5)+e.
// Swapped QK: mfma(K,Q) -> D[key][q]; lane owns q-col ql=lane&31, denom lane-local.
// Q pre-scaled by log2(e)/8 -> p = exp2(score) (raw v_exp_f32).
__global__ __launch_bounds__(256)
void attn_mfma(const bf16* __restrict__ Q, const bf16* __restrict__ K,
               const bf16* __restrict__ Vt, const int* __restrict__ mask,
               bf16* __restrict__ ctx)
{
    __shared__ bf16 Ks[2][64][64];
    __shared__ bf16 Vs[2][64][64];
    __shared__ bf16 Ps[4][32*72];    // per-wave P[q][key], stride 144B (16B-aligned)

    const int tid  = threadIdx.x;
    const int lane = tid & 63;
    const int w    = tid >> 6;       // 0..3
    const int ql   = lane & 31;
    const int hi   = lane >> 5;
    const int bh   = blockIdx.y;
    const int b    = bh >> 4;
    const int h    = bh & 15;
    const int q0   = blockIdx.x * 128;

    const bf16* Qb = Q  + (size_t)bh * Sn * DKn;
    const bf16* Kb = K  + (size_t)bh * Sn * DKn;
    const bf16* Vb = Vt + (size_t)bh * DKn * Sn;
    const int4* mb4 = (const int4*)(mask + b * Sn);

    // staging: thread stages 2 K-chunks + 2 V-chunks (rows r0 and r0+32)
    const int sr   = lane >> 3;
    const int scol = 8 * ((lane & 7) ^ sr);
    const int r0   = w * 8 + sr;
    const bf16* gK = Kb + (size_t)r0 * DKn + scol;
    const bf16* gV = Vb + (size_t)r0 * Sn  + scol;
    const int swz  = (ql & 7) << 3;

    // Q B-frags (4 d-steps), in registers for the whole kernel
    bf16x8 bq[4];
    {
        const bf16* qrow = Qb + (size_t)(q0 + w*32 + ql) * DKn + 8*hi;
        #pragma unroll
        for (int ds = 0; ds < 4; ++ds)
            bq[ds] = *(const bf16x8*)(qrow + 16*ds);
    }

    f32x16 o[2];
    #pragma unroll
    for (int dt = 0; dt < 2; ++dt)
        #pragma unroll
        for (int e = 0; e < 16; ++e) o[dt][e] = 0.f;
    float lq = 0.f;

    // prologue: stage tile 0
    glds16(gK,            &Ks[0][w*8     ][0]);
    glds16(gK + 32*DKn,   &Ks[0][w*8 + 32][0]);
    glds16(gV,            &Vs[0][w*8     ][0]);
    glds16(gV + 32*Sn,    &Vs[0][w*8 + 32][0]);
    __syncthreads();

    int bf = 0;
    for (int kt = 0; kt < Sn/64; ++kt) {
        if (kt + 1 < Sn/64) {
            const bf16* nK = gK + (size_t)(kt+1)*64*DKn;
            const bf16* nV = gV + (kt+1)*64;
            glds16(nK,          &Ks[bf^1][w*8     ][0]);
            glds16(nK + 32*DKn, &Ks[bf^1][w*8 + 32][0]);
            glds16(nV,          &Vs[bf^1][w*8     ][0]);
            glds16(nV + 32*Sn,  &Vs[bf^1][w*8 + 32][0]);
        }

        // QK^T (swapped) over two 32-key tiles
        #pragma unroll
        for (int kt2 = 0; kt2 < 2; ++kt2) {
            f32x16 z;
            #pragma unroll
            for (int e = 0; e < 16; ++e) z[e] = 0.f;
            #pragma unroll
            for (int ds = 0; ds < 4; ++ds) {
                bf16x8 kf = *(const bf16x8*)
                    &Ks[bf][32*kt2 + ql][(16*ds + 8*hi) ^ swz];
                z = mfma32(kf, bq[ds], z);
            }
            // fixed-C softmax; lane's rows = keys (r&3)+8*(r>>2)+4*hi (+32*kt2)
            #pragma unroll
            for (int j = 0; j < 4; ++j) {
                int kbase = 8*j + 4*hi + 32*kt2;       // 4-key run
                int4 m4 = mb4[kt*16 + (kbase >> 2)];
                bf16x4 pk;
                pk[0] = (bf16)(m4.x ? exp2f(z[4*j+0]) : 0.f);
                pk[1] = (bf16)(m4.y ? exp2f(z[4*j+1]) : 0.f);
                pk[2] = (bf16)(m4.z ? exp2f(z[4*j+2]) : 0.f);
                pk[3] = (bf16)(m4.w ? exp2f(z[4*j+3]) : 0.f);
                lq += (float)pk[0] + (float)pk[1] + (float)pk[2] + (float)pk[3];
                *(bf16x4*)&Ps[w][ql*72 + kbase] = pk;  // b64, ~2-way banks
            }
        }

        // PV: A = P rows (q=ql), B = V^T tile
        bf16x8 pa[4];
        #pragma unroll
        for (int ks = 0; ks < 4; ++ks)
            pa[ks] = *(const bf16x8*)&Ps[w][ql*72 + 16*ks + 8*hi];
        #pragma unroll
        for (int dt = 0; dt < 2; ++dt)
            #pragma unroll
            for (int ks = 0; ks < 4; ++ks) {
                bf16x8 vf = *(const bf16x8*)
                    &Vs[bf][32*dt + ql][(16*ks + 8*hi) ^ swz];
                o[dt] = mfma32(pa[ks], vf, o[dt]);
            }

        __syncthreads();
        bf ^= 1;
    }

    // denominators: lanes ql and ql+32 hold the two halves of q-row ql
    lq += __shfl_xor(lq, 32);
    float inv[16];
    #pragma unroll
    for (int r = 0; r < 16; ++r) {
        int qr = (r & 3) + 8*(r >> 2) + 4*hi;
        inv[r] = 1.0f / __shfl(lq, qr);
    }

    #pragma unroll
    for (int dt = 0; dt < 2; ++dt)
        #pragma unroll
        for (int r = 0; r < 16; ++r) {
            int qr = (r & 3) + 8*(r >> 2) + 4*hi;
            int s_ = q0 + w*32 + qr;
            ctx[(size_t)(b*Sn + s_) * Dn + h*64 + 32*dt + ql] =
                (bf16)(o[dt][r] * inv[r]);
        }
}

extern "C" void kernel_launch(void* const* d_in, const int* in_sizes, int n_in,
                              void* d_out, int out_size, void* d_ws, size_t ws_size,
                              hipStream_t stream) {
    const float* q_in = (const float*)d_in[0];
    const float* k_in = (const float*)d_in[1];
    const float* v_in = (const float*)d_in[2];
    const int*   mask = (const int*)  d_in[3];
    const float* w_q  = (const float*)d_in[4];
    const float* b_q  = (const float*)d_in[5];
    const float* w_k  = (const float*)d_in[6];
    const float* b_k  = (const float*)d_in[7];
    const float* w_v  = (const float*)d_in[8];
    const float* b_v  = (const float*)d_in[9];
    const float* w_o  = (const float*)d_in[10];
    const float* b_o  = (const float*)d_in[11];

    char* ws = (char*)d_ws;
    bf16* Abf_q = (bf16*)(ws);
    bf16* Abf_k = (bf16*)(ws + 8388608);
    bf16* Abf_v = (bf16*)(ws + 16777216);
    bf16* ctx   = (bf16*)(ws);                // aliases Abf_q after proj consumes it
    bf16* Qh    = (bf16*)(ws + 25165824);
    bf16* Kh    = (bf16*)(ws + 33554432);
    bf16* Vt    = (bf16*)(ws + 41943040);
    bf16* Wbf_q = (bf16*)(ws + 50331648);
    bf16* Wbf_k = (bf16*)(ws + 52428800);
    bf16* Wbf_v = (bf16*)(ws + 54525952);
    bf16* Wbf_o = (bf16*)(ws + 56623104);

    dim3 blk(256);
    conv3<<<dim3(2048, 3), blk, 0, stream>>>(q_in, k_in, v_in, Abf_q, Abf_k, Abf_v);
    conv_w<<<dim3(512, 4), blk, 0, stream>>>(w_q, w_k, w_v, w_o,
                                             Wbf_q, Wbf_k, Wbf_v, Wbf_o);

    gemm_proj<<<dim3(768), blk, 0, stream>>>(
        Abf_q, Abf_k, Abf_v, Wbf_q, Wbf_k, Wbf_v, b_q, b_k, b_v, Qh, Kh, Vt);

    attn_mfma<<<dim3(Sn/128, Bn*Hn), blk, 0, stream>>>(Qh, Kh, Vt, mask, ctx);

    gemm_out<<<dim3(512), blk, 0, stream>>>(ctx, Wbf_o, b_o, (float*)d_out);
}

// Round 9
// 148.555 us; speedup vs baseline: 1.2705x; 1.2705x over previous
//
#include <hip/hip_runtime.h>
#include <math.h>

#define Bn 2
#define Sn 2048
#define Dn 1024
#define Hn 16
#define DKn 64
#define Mn (Bn*Sn)

typedef __bf16 bf16;
typedef __attribute__((ext_vector_type(8))) __bf16 bf16x8;
typedef __attribute__((ext_vector_type(4))) __bf16 bf16x4;
typedef __attribute__((ext_vector_type(4))) float f32x4;

__device__ inline f32x4 mfma16(bf16x8 a, bf16x8 b, f32x4 c) {
    return __builtin_amdgcn_mfma_f32_16x16x32_bf16(a, b, c, 0, 0, 0);
}

typedef __attribute__((address_space(3))) void lds_t;
typedef const __attribute__((address_space(1))) void gbl_t;
__device__ __forceinline__ void glds16(const void* g, void* l) {
    __builtin_amdgcn_global_load_lds((gbl_t*)g, (lds_t*)l, 16, 0, 0);
}

// ---------- converts ----------
__global__ __launch_bounds__(256)
void conv3(const float* __restrict__ s0, const float* __restrict__ s1,
           const float* __restrict__ s2, bf16* __restrict__ d0,
           bf16* __restrict__ d1, bf16* __restrict__ d2)
{
    const float* s = blockIdx.y == 0 ? s0 : blockIdx.y == 1 ? s1 : s2;
    bf16*       d = blockIdx.y == 0 ? d0 : blockIdx.y == 1 ? d1 : d2;
    int i = (blockIdx.x * 256 + threadIdx.x) * 8;
    float4 a = *(const float4*)(s + i);
    float4 b = *(const float4*)(s + i + 4);
    bf16x8 o;
    o[0]=(bf16)a.x; o[1]=(bf16)a.y; o[2]=(bf16)a.z; o[3]=(bf16)a.w;
    o[4]=(bf16)b.x; o[5]=(bf16)b.y; o[6]=(bf16)b.z; o[7]=(bf16)b.w;
    *(bf16x8*)(d + i) = o;
}

__global__ __launch_bounds__(256)
void conv_w(const float* __restrict__ s0, const float* __restrict__ s1,
            const float* __restrict__ s2, const float* __restrict__ s3,
            bf16* __restrict__ d0, bf16* __restrict__ d1,
            bf16* __restrict__ d2, bf16* __restrict__ d3)
{
    const float* s = blockIdx.y == 0 ? s0 : blockIdx.y == 1 ? s1 :
                     blockIdx.y == 2 ? s2 : s3;
    bf16*       d = blockIdx.y == 0 ? d0 : blockIdx.y == 1 ? d1 :
                     blockIdx.y == 2 ? d2 : d3;
    int i = (blockIdx.x * 256 + threadIdx.x) * 8;
    float4 a = *(const float4*)(s + i);
    float4 b = *(const float4*)(s + i + 4);
    bf16x8 o;
    o[0]=(bf16)a.x; o[1]=(bf16)a.y; o[2]=(bf16)a.z; o[3]=(bf16)a.w;
    o[4]=(bf16)b.x; o[5]=(bf16)b.y; o[6]=(bf16)b.z; o[7]=(bf16)b.w;
    *(bf16x8*)(d + i) = o;
}

// ---------- mask scan: permutation pos[b][s] (unmasked first), cnt[b] ----------
__global__ __launch_bounds__(64)
void mask_scan(const int* __restrict__ mask, int* __restrict__ pos,
               int* __restrict__ cnt)
{
    const int b    = blockIdx.x;
    const int lane = threadIdx.x;            // one wave per batch
    const int* mb  = mask + b * Sn;
    int loc[32];
    int c = 0;
    #pragma unroll
    for (int e = 0; e < 32; ++e) {
        loc[e] = (mb[lane * 32 + e] != 0) ? 1 : 0;
        c += loc[e];
    }
    int pre = c;
    #pragma unroll
    for (int off = 1; off < 64; off <<= 1) {
        int v = __shfl_up(pre, off);
        if (lane >= off) pre += v;
    }
    int excl  = pre - c;
    int total = __shfl(pre, 63);
    int un = excl;
    int ms = lane * 32 - excl;               // masked-before count
    #pragma unroll
    for (int e = 0; e < 32; ++e) {
        int pv;
        if (loc[e]) { pv = un; ++un; } else { pv = total + ms; ++ms; }
        pos[b * Sn + lane * 32 + e] = pv;
    }
    if (lane == 63) cnt[b] = total;
}

// ---------- projection GEMM: C = A[4096,1024] @ W[1024,1024]^T + bias ----------
// z==0: Q, bf16 [B,H,S,DK] scaled log2(e)/8 (folds QK scale + exp->exp2);
// z==1: K, bf16 [B,H,slot,DK] (rows permuted by pos);
// z==2: V, bf16 [B,H,DK,slot] (columns permuted by pos).
__global__ __launch_bounds__(256)
void gemm_proj(const bf16* __restrict__ Aq, const bf16* __restrict__ Ak,
               const bf16* __restrict__ Av, const bf16* __restrict__ Wq,
               const bf16* __restrict__ Wk, const bf16* __restrict__ Wv,
               const float* __restrict__ bq, const float* __restrict__ bk,
               const float* __restrict__ bv, const int* __restrict__ pos,
               bf16* __restrict__ Cq, bf16* __restrict__ Ck, bf16* __restrict__ Cv)
{
    __shared__ bf16 As[128][32];
    __shared__ bf16 Ws_[128][32];

    const int bid = blockIdx.x;
    const int l   = (bid & 7) * 96 + (bid >> 3);   // bijective (768 % 8 == 0)
    const int z   = l >> 8;
    const int rem = l & 255;
    const int m0  = (rem >> 3) * 128;
    const int n0  = (rem & 7) * 128;

    const bf16*  A    = z == 0 ? Aq : z == 1 ? Ak : Av;
    const bf16*  W    = z == 0 ? Wq : z == 1 ? Wk : Wv;
    const float* bias = z == 0 ? bq : z == 1 ? bk : bv;
    bf16*        C    = z == 0 ? Cq : z == 1 ? Ck : Cv;

    const int tid = threadIdx.x;
    const int w4 = tid >> 6, ln = tid & 63;
    const int p = ln & 15, g = ln >> 4;
    const int wr = w4 >> 1, wc = w4 & 1;

    const int arow = w4 * 32 + (ln >> 2);
    const int acol = (ln & 3) * 8;
    const bf16* ga = A + (size_t)(m0 + arow) * Dn + acol;
    const bf16* gw = W + (size_t)(n0 + arow) * Dn + acol;

    f32x4 acc[4][4];
    #pragma unroll
    for (int mi = 0; mi < 4; ++mi)
        #pragma unroll
        for (int ni = 0; ni < 4; ++ni) acc[mi][ni] = (f32x4){0.f,0.f,0.f,0.f};

    for (int k0 = 0; k0 < Dn; k0 += 32) {
        __syncthreads();
        glds16(ga + k0,           &As [w4*32     ][0]);
        glds16(ga + k0 + 16*Dn,   &As [w4*32 + 16][0]);
        glds16(gw + k0,           &Ws_[w4*32     ][0]);
        glds16(gw + k0 + 16*Dn,   &Ws_[w4*32 + 16][0]);
        __syncthreads();

        bf16x8 af[4], bfr[4];
        #pragma unroll
        for (int mi = 0; mi < 4; ++mi)
            af[mi] = *(const bf16x8*)&As[wr*64 + mi*16 + p][g*8];
        #pragma unroll
        for (int ni = 0; ni < 4; ++ni)
            bfr[ni] = *(const bf16x8*)&Ws_[wc*64 + ni*16 + p][g*8];
        #pragma unroll
        for (int mi = 0; mi < 4; ++mi)
            #pragma unroll
            for (int ni = 0; ni < 4; ++ni)
                acc[mi][ni] = mfma16(af[mi], bfr[ni], acc[mi][ni]);
    }

    if (z == 0) {
        const float osc = 0.18033688011112042f;   // log2(e)/8
        #pragma unroll
        for (int ni = 0; ni < 4; ++ni) {
            int n = n0 + wc*64 + ni*16 + p;
            int h = n >> 6, dk = n & (DKn - 1);
            float bv = bias[n];
            #pragma unroll
            for (int mi = 0; mi < 4; ++mi)
                #pragma unroll
                for (int r = 0; r < 4; ++r) {
                    int m = m0 + wr*64 + mi*16 + 4*g + r;
                    int b = m >> 11, s = m & (Sn - 1);
                    C[(((size_t)(b*Hn + h)*Sn + s)*DKn) + dk] =
                        (bf16)((acc[mi][ni][r] + bv) * osc);
                }
        }
    } else {
        int slots[4][4];
        #pragma unroll
        for (int mi = 0; mi < 4; ++mi)
            #pragma unroll
            for (int r = 0; r < 4; ++r) {
                int m = m0 + wr*64 + mi*16 + 4*g + r;
                int b = m >> 11, s = m & (Sn - 1);
                slots[mi][r] = pos[b*Sn + s];
            }
        if (z == 1) {
            #pragma unroll
            for (int ni = 0; ni < 4; ++ni) {
                int n = n0 + wc*64 + ni*16 + p;
                int h = n >> 6, dk = n & (DKn - 1);
                float bv = bias[n];
                #pragma unroll
                for (int mi = 0; mi < 4; ++mi)
                    #pragma unroll
                    for (int r = 0; r < 4; ++r) {
                        int m = m0 + wr*64 + mi*16 + 4*g + r;
                        int b = m >> 11;
                        C[(((size_t)(b*Hn + h)*Sn + slots[mi][r])*DKn) + dk] =
                            (bf16)(acc[mi][ni][r] + bv);
                    }
            }
        } else {
            #pragma unroll
            for (int ni = 0; ni < 4; ++ni) {
                int n = n0 + wc*64 + ni*16 + p;
                int h = n >> 6, dk = n & (DKn - 1);
                float bv = bias[n];
                #pragma unroll
                for (int mi = 0; mi < 4; ++mi)
                    #pragma unroll
                    for (int r = 0; r < 4; ++r) {
                        int m = m0 + wr*64 + mi*16 + 4*g + r;
                        int b = m >> 11;
                        C[(((size_t)(b*Hn + h)*DKn + dk)*Sn) + slots[mi][r]] =
                            (bf16)(acc[mi][ni][r] + bv);
                    }
            }
        }
    }
}

// ---------- output GEMM (unchanged) ----------
__global__ __launch_bounds__(256)
void gemm_out(const bf16* __restrict__ A, const bf16* __restrict__ W,
              const float* __restrict__ bias, float* __restrict__ C)
{
    __shared__ bf16 As[128][32];
    __shared__ bf16 Ws_[64][32];

    const int bid = blockIdx.x;
    const int l   = (bid & 7) * 64 + (bid >> 3);
    const int m0  = (l >> 4) * 128;
    const int n0  = (l & 15) * 64;

    const int tid = threadIdx.x;
    const int w4 = tid >> 6, ln = tid & 63;
    const int p = ln & 15, g = ln >> 4;
    const int wr = w4 >> 1, wc = w4 & 1;

    const int arow = w4 * 32 + (ln >> 2);
    const int acol = (ln & 3) * 8;
    const bf16* ga = A + (size_t)(m0 + arow) * Dn + acol;
    const bf16* gw = W + (size_t)(n0 + w4*16 + (ln >> 2)) * Dn + acol;

    f32x4 acc[4][2];
    #pragma unroll
    for (int mi = 0; mi < 4; ++mi)
        #pragma unroll
        for (int ni = 0; ni < 2; ++ni) acc[mi][ni] = (f32x4){0.f,0.f,0.f,0.f};

    for (int k0 = 0; k0 < Dn; k0 += 32) {
        __syncthreads();
        glds16(ga + k0,          &As [w4*32     ][0]);
        glds16(ga + k0 + 16*Dn,  &As [w4*32 + 16][0]);
        glds16(gw + k0,          &Ws_[w4*16     ][0]);
        __syncthreads();

        bf16x8 af[4], bfr[2];
        #pragma unroll
        for (int mi = 0; mi < 4; ++mi)
            af[mi] = *(const bf16x8*)&As[wr*64 + mi*16 + p][g*8];
        #pragma unroll
        for (int ni = 0; ni < 2; ++ni)
            bfr[ni] = *(const bf16x8*)&Ws_[wc*32 + ni*16 + p][g*8];
        #pragma unroll
        for (int mi = 0; mi < 4; ++mi)
            #pragma unroll
            for (int ni = 0; ni < 2; ++ni)
                acc[mi][ni] = mfma16(af[mi], bfr[ni], acc[mi][ni]);
    }

    #pragma unroll
    for (int ni = 0; ni < 2; ++ni) {
        int n = n0 + wc*32 + ni*16 + p;
        float bv = bias[n];
        #pragma unroll
        for (int mi = 0; mi < 4; ++mi)
            #pragma unroll
            for (int r = 0; r < 4; ++r) {
                int m = m0 + wr*64 + mi*16 + 4*g + r;
                C[(size_t)m * Dn + n] = acc[mi][ni][r] + bv;
            }
    }
}

// ---------- MFMA flash attention on COMPACTED keys ----------
// r7 structure: 512 thr = 8 waves x 16 q-rows; swapped QK^T; dbuf K/V; 1 barrier/iter.
// Keys permuted so unmasked keys occupy slots [0,cnt); loop nt=ceil(cnt/64) tiles;
// validity test (slot<cnt) only on the tail tile. cnt==0 -> uniform p=1 over all S.
__global__ __launch_bounds__(512)
void attn_mfma(const bf16* __restrict__ Q, const bf16* __restrict__ K,
               const bf16* __restrict__ Vt, const int* __restrict__ cnt,
               bf16* __restrict__ ctx)
{
    __shared__ bf16 Ks[2][64][64];
    __shared__ bf16 Vs[2][64][64];
    __shared__ bf16 Ps[8][16][72];   // per-wave P: [qrow][key], stride 144B

    const int tid  = threadIdx.x;
    const int lane = tid & 63;
    const int w    = tid >> 6;
    const int g    = lane >> 4;
    const int p    = lane & 15;
    const int bh   = blockIdx.y;
    const int b    = bh >> 4;
    const int h    = bh & 15;
    const int q0   = blockIdx.x * 128;

    const int  cntb = cnt[b];
    const bool unif = (cntb == 0);
    const int  nt   = unif ? (Sn / 64) : ((cntb + 63) >> 6);

    const bf16* Qb = Q  + (size_t)bh * Sn * DKn;
    const bf16* Kb = K  + (size_t)bh * Sn * DKn;
    const bf16* Vb = Vt + (size_t)bh * DKn * Sn;

    const int sr   = lane >> 3;
    const int scol = 8 * ((lane & 7) ^ sr);
    const int drow = w * 8 + sr;
    const int swzk = (p & 7) << 3;
    const bf16* gK = Kb + (size_t)drow * DKn + scol;
    const bf16* gV = Vb + (size_t)drow * Sn  + scol;

    bf16x8 aq0, aq1;
    {
        const bf16* qrow = Qb + (size_t)(q0 + w*16 + p) * DKn + 8*g;
        aq0 = *(const bf16x8*)(qrow);
        aq1 = *(const bf16x8*)(qrow + 32);
    }

    f32x4 o[4];
    #pragma unroll
    for (int dt = 0; dt < 4; ++dt) o[dt] = (f32x4){0.f,0.f,0.f,0.f};
    float lq = 0.f;

    glds16(gK, &Ks[0][w*8][0]);
    glds16(gV, &Vs[0][w*8][0]);
    __syncthreads();

    int bf = 0;
    for (int kt = 0; kt < nt; ++kt) {
        if (kt + 1 < nt) {
            glds16(gK + (size_t)(kt+1)*64*DKn, &Ks[bf^1][w*8][0]);
            glds16(gV + (size_t)(kt+1)*64,     &Vs[bf^1][w*8][0]);
        }

        const bool tail = (!unif) && (kt == nt - 1);
        const int  rem  = cntb - (kt << 6);

        #pragma unroll
        for (int t = 0; t < 4; ++t) {
            f32x4 z = (f32x4){0.f,0.f,0.f,0.f};
            bf16x8 k0 = *(const bf16x8*)&Ks[bf][16*t + p][(8*g)      ^ swzk];
            bf16x8 k1 = *(const bf16x8*)&Ks[bf][16*t + p][(8*g + 32) ^ swzk];
            z = mfma16(k0, aq0, z);
            z = mfma16(k1, aq1, z);
            bf16x4 pk;
            if (unif) {
                pk[0] = (bf16)1.f; pk[1] = (bf16)1.f;
                pk[2] = (bf16)1.f; pk[3] = (bf16)1.f;
                lq += 4.f;
            } else if (tail) {
                int kb = 16*t + 4*g;
                pk[0] = (bf16)(kb + 0 < rem ? exp2f(z[0]) : 0.f);
                pk[1] = (bf16)(kb + 1 < rem ? exp2f(z[1]) : 0.f);
                pk[2] = (bf16)(kb + 2 < rem ? exp2f(z[2]) : 0.f);
                pk[3] = (bf16)(kb + 3 < rem ? exp2f(z[3]) : 0.f);
                lq += (float)pk[0] + (float)pk[1] + (float)pk[2] + (float)pk[3];
            } else {
                pk[0] = (bf16)exp2f(z[0]);
                pk[1] = (bf16)exp2f(z[1]);
                pk[2] = (bf16)exp2f(z[2]);
                pk[3] = (bf16)exp2f(z[3]);
                lq += (float)pk[0] + (float)pk[1] + (float)pk[2] + (float)pk[3];
            }
            *(bf16x4*)&Ps[w][p][16*t + 4*g] = pk;
        }

        bf16x8 pa0 = *(const bf16x8*)&Ps[w][p][8*g];
        bf16x8 pa1 = *(const bf16x8*)&Ps[w][p][32 + 8*g];
        #pragma unroll
        for (int dt = 0; dt < 4; ++dt) {
            bf16x8 v0 = *(const bf16x8*)&Vs[bf][16*dt + p][(8*g)      ^ swzk];
            bf16x8 v1 = *(const bf16x8*)&Vs[bf][16*dt + p][(8*g + 32) ^ swzk];
            o[dt] = mfma16(pa0, v0, o[dt]);
            o[dt] = mfma16(pa1, v1, o[dt]);
        }

        __syncthreads();
        bf ^= 1;
    }

    lq += __shfl_xor(lq, 16);
    lq += __shfl_xor(lq, 32);
    float ld[4];
    #pragma unroll
    for (int r = 0; r < 4; ++r) ld[r] = __shfl(lq, 4*g + r);

    #pragma unroll
    for (int dt = 0; dt < 4; ++dt)
        #pragma unroll
        for (int r = 0; r < 4; ++r) {
            int s_ = q0 + w*16 + 4*g + r;
            ctx[(size_t)(b*Sn + s_) * Dn + h*64 + 16*dt + p] =
                (bf16)(o[dt][r] / ld[r]);
        }
}

extern "C" void kernel_launch(void* const* d_in, const int* in_sizes, int n_in,
                              void* d_out, int out_size, void* d_ws, size_t ws_size,
                              hipStream_t stream) {
    const float* q_in = (const float*)d_in[0];
    const float* k_in = (const float*)d_in[1];
    const float* v_in = (const float*)d_in[2];
    const int*   mask = (const int*)  d_in[3];
    const float* w_q  = (const float*)d_in[4];
    const float* b_q  = (const float*)d_in[5];
    const float* w_k  = (const float*)d_in[6];
    const float* b_k  = (const float*)d_in[7];
    const float* w_v  = (const float*)d_in[8];
    const float* b_v  = (const float*)d_in[9];
    const float* w_o  = (const float*)d_in[10];
    const float* b_o  = (const float*)d_in[11];

    char* ws = (char*)d_ws;
    bf16* Abf_q = (bf16*)(ws);
    bf16* Abf_k = (bf16*)(ws + 8388608);
    bf16* Abf_v = (bf16*)(ws + 16777216);
    bf16* ctx   = (bf16*)(ws);                // aliases Abf_q after proj consumes it
    bf16* Qh    = (bf16*)(ws + 25165824);
    bf16* Kh    = (bf16*)(ws + 33554432);
    bf16* Vt    = (bf16*)(ws + 41943040);
    bf16* Wbf_q = (bf16*)(ws + 50331648);
    bf16* Wbf_k = (bf16*)(ws + 52428800);
    bf16* Wbf_v = (bf16*)(ws + 54525952);
    bf16* Wbf_o = (bf16*)(ws + 56623104);
    int*  pos   = (int*) (ws + 58720256);     // [B][S]
    int*  cntb  = (int*) (ws + 58736640);     // [B]

    dim3 blk(256);
    conv3<<<dim3(2048, 3), blk, 0, stream>>>(q_in, k_in, v_in, Abf_q, Abf_k, Abf_v);
    conv_w<<<dim3(512, 4), blk, 0, stream>>>(w_q, w_k, w_v, w_o,
                                             Wbf_q, Wbf_k, Wbf_v, Wbf_o);
    mask_scan<<<dim3(Bn), dim3(64), 0, stream>>>(mask, pos, cntb);

    gemm_proj<<<dim3(768), blk, 0, stream>>>(
        Abf_q, Abf_k, Abf_v, Wbf_q, Wbf_k, Wbf_v, b_q, b_k, b_v, pos, Qh, Kh, Vt);

    attn_mfma<<<dim3(Sn/128, Bn*Hn), dim3(512), 0, stream>>>(Qh, Kh, Vt, cntb, ctx);

    gemm_out<<<dim3(512), blk, 0, stream>>>(ctx, Wbf_o, b_o, (float*)d_out);
}